// Round 6
// baseline (221.923 us; speedup 1.0000x reference)
//
#include <hip/hip_runtime.h>
#include <hip/hip_cooperative_groups.h>
#include <hip/hip_fp8.h>

namespace cg = cooperative_groups;

#define NV 4
#define NB 2048
#define ND 512
#define NN 8192
// sim = cos/TEMP, TEMP=0.5 -> scale 2.0

typedef int int8v __attribute__((ext_vector_type(8)));
typedef int int4v __attribute__((ext_vector_type(4)));
typedef float floatx4 __attribute__((ext_vector_type(4)));
#define SCALE1 0x7F7F7F7Fu  // E8M0 bytes 127 -> 2^0 = 1.0

// ============================================================================
// R13: ONE fused cooperative kernel.
// Across R7..R12, dur_us - sim_k == ~62 µs CONSTANT while normalize+finalize
// roofline at ~6 µs total -> the residual is launch/gap overhead of the
// 3-kernel chain, now larger than sim_k itself. Fuse: persistent 512 blocks
// (2/CU guaranteed: 32 KiB LDS, ~110 VGPR), grid.sync() between phases.
// Sim phase = R7's proven 48.2 µs body, UNCHANGED (tile 128², 256 thr,
// reg-prefetch staging, rolled kt loop, swizzled LDS — absmax 0 verified).
// Hedge: if cooperative launch errors (capture/size), fall back to the
// original 3-kernel path so the bench still passes.
// ============================================================================

// ---------------- sim tile body constants (R7) ------------------------------
// LDS swizzle: row r, 16B chunk c at r*128 + (c^(r&7))*16 (both sides).

__global__ __launch_bounds__(256) void fused_k(const float* __restrict__ x,
                                               unsigned char* __restrict__ xn,
                                               float* __restrict__ sumexp,
                                               float* __restrict__ pos,
                                               float* __restrict__ out) {
  __shared__ unsigned char As[128 * 128];
  __shared__ unsigned char Bs[128 * 128];
  cg::grid_group grid = cg::this_grid();

  const int tid = threadIdx.x;
  const int bid0 = blockIdx.x;  // 0..511

  // ===================== phase 1: normalize + zero ==========================
  {
    const int gid = bid0 * 256 + tid;
    if (gid < NN) sumexp[gid] = 0.0f;
    if (gid == 0) out[0] = 0.0f;

    const int wg = bid0 * 4 + (tid >> 6);  // wave id 0..2047
    const int l = tid & 63;
#pragma unroll 1
    for (int i = 0; i < 4; ++i) {
      const int row = wg + 2048 * i;  // 4 rows per wave, coalesced across waves
      const float4* xr = (const float4*)(x + (size_t)row * ND);
      float4 v0 = xr[l * 2 + 0];
      float4 v1 = xr[l * 2 + 1];
      float ss = v0.x * v0.x + v0.y * v0.y + v0.z * v0.z + v0.w * v0.w +
                 v1.x * v1.x + v1.y * v1.y + v1.z * v1.z + v1.w * v1.w;
#pragma unroll
      for (int off = 32; off > 0; off >>= 1) ss += __shfl_xor(ss, off, 64);
      const float inv = 1.0f / fmaxf(sqrtf(ss), 1e-8f);
      union { unsigned char b[8]; uint2 u; } pk;
      pk.b[0] = __hip_fp8_e4m3(v0.x * inv).__x;
      pk.b[1] = __hip_fp8_e4m3(v0.y * inv).__x;
      pk.b[2] = __hip_fp8_e4m3(v0.z * inv).__x;
      pk.b[3] = __hip_fp8_e4m3(v0.w * inv).__x;
      pk.b[4] = __hip_fp8_e4m3(v1.x * inv).__x;
      pk.b[5] = __hip_fp8_e4m3(v1.y * inv).__x;
      pk.b[6] = __hip_fp8_e4m3(v1.z * inv).__x;
      pk.b[7] = __hip_fp8_e4m3(v1.w * inv).__x;
      *(uint2*)(xn + (size_t)row * ND + l * 8) = pk.u;
    }
  }

  grid.sync();  // xn complete, sumexp/out zeroed

  // ===================== phase 2: sim tiles (R7 body) =======================
  {
    const int l = tid & 63;
    const int m = l & 15, q = l >> 4, s = l & 7;
    const int wr = (tid >> 6) >> 1, wc = (tid >> 6) & 1;
    const int crow = tid >> 3;
    const int coff = (tid & 7) * 16;
    const int lsw = ((tid & 7) ^ ((tid >> 3) & 7)) * 16;
    const int fo0 = ((2 * q + 0) ^ s) * 16;
    const int fo1 = ((2 * q + 1) ^ s) * 16;

#pragma unroll 1
    for (int tt = bid0; tt < 2080; tt += 512) {
      // XCD swizzle of tile id (2080 = 8*260, bijective)
      const int bid = (tt & 7) * 260 + (tt >> 3);
      // triangular decode: bid -> (rt, ct), rt <= ct
      int rt = (int)((129.0f - sqrtf(16641.0f - 8.0f * (float)bid)) * 0.5f);
      rt = rt < 0 ? 0 : (rt > 63 ? 63 : rt);
      while (rt > 0 && (rt * 64 - rt * (rt - 1) / 2) > bid) --rt;
      while (rt < 63 && ((rt + 1) * 64 - (rt + 1) * rt / 2) <= bid) ++rt;
      const int ct = rt + (bid - (rt * 64 - rt * (rt - 1) / 2));
      const bool diag = (rt == ct);

      floatx4 acc[4][4] = {};
      const unsigned char* gA = xn + (size_t)rt * 128 * ND;
      const unsigned char* gB = xn + (size_t)ct * 128 * ND;

      int4v pA[4], pB[4];
#pragma unroll
      for (int i = 0; i < 4; ++i) {  // prologue: prefetch kt=0
        const size_t go = (size_t)(i * 32 + crow) * ND + coff;
        pA[i] = *(const int4v*)(gA + go);
        pB[i] = *(const int4v*)(gB + go);
      }

#pragma unroll 1  // rolled (R5/R6/R10 lesson: unroll -> addr hoist -> spill)
      for (int kt = 0; kt < 4; ++kt) {
#pragma unroll
        for (int i = 0; i < 4; ++i) {  // stage current kt
          const int la = (i * 32 + crow) * 128 + lsw;
          *(int4v*)(As + la) = pA[i];
          *(int4v*)(Bs + la) = pB[i];
        }
        __syncthreads();
        if (kt < 3) {  // prefetch kt+1 — in flight across MFMA phase
          const int kb = (kt + 1) * 128;
#pragma unroll
          for (int i = 0; i < 4; ++i) {
            const size_t go = (size_t)(i * 32 + crow) * ND + kb + coff;
            pA[i] = *(const int4v*)(gA + go);
            pB[i] = *(const int4v*)(gB + go);
          }
        }
        int8v af0, af1, af2, af3, bf0, bf1, bf2, bf3;
        {
          const unsigned char* pa0 = As + (wr * 64 + 0 * 16 + m) * 128;
          const unsigned char* pa1 = As + (wr * 64 + 1 * 16 + m) * 128;
          const unsigned char* pa2 = As + (wr * 64 + 2 * 16 + m) * 128;
          const unsigned char* pa3 = As + (wr * 64 + 3 * 16 + m) * 128;
          const unsigned char* pb0 = Bs + (wc * 64 + 0 * 16 + m) * 128;
          const unsigned char* pb1 = Bs + (wc * 64 + 1 * 16 + m) * 128;
          const unsigned char* pb2 = Bs + (wc * 64 + 2 * 16 + m) * 128;
          const unsigned char* pb3 = Bs + (wc * 64 + 3 * 16 + m) * 128;
          af0 = __builtin_shufflevector(*(const int4v*)(pa0 + fo0),
                                        *(const int4v*)(pa0 + fo1), 0,1,2,3,4,5,6,7);
          af1 = __builtin_shufflevector(*(const int4v*)(pa1 + fo0),
                                        *(const int4v*)(pa1 + fo1), 0,1,2,3,4,5,6,7);
          af2 = __builtin_shufflevector(*(const int4v*)(pa2 + fo0),
                                        *(const int4v*)(pa2 + fo1), 0,1,2,3,4,5,6,7);
          af3 = __builtin_shufflevector(*(const int4v*)(pa3 + fo0),
                                        *(const int4v*)(pa3 + fo1), 0,1,2,3,4,5,6,7);
          bf0 = __builtin_shufflevector(*(const int4v*)(pb0 + fo0),
                                        *(const int4v*)(pb0 + fo1), 0,1,2,3,4,5,6,7);
          bf1 = __builtin_shufflevector(*(const int4v*)(pb1 + fo0),
                                        *(const int4v*)(pb1 + fo1), 0,1,2,3,4,5,6,7);
          bf2 = __builtin_shufflevector(*(const int4v*)(pb2 + fo0),
                                        *(const int4v*)(pb2 + fo1), 0,1,2,3,4,5,6,7);
          bf3 = __builtin_shufflevector(*(const int4v*)(pb3 + fo0),
                                        *(const int4v*)(pb3 + fo1), 0,1,2,3,4,5,6,7);
        }
#define MFMA_ROW(mt, afv)                                                     \
  acc[mt][0] = __builtin_amdgcn_mfma_scale_f32_16x16x128_f8f6f4(              \
      afv, bf0, acc[mt][0], 0, 0, 0, SCALE1, 0, SCALE1);                      \
  acc[mt][1] = __builtin_amdgcn_mfma_scale_f32_16x16x128_f8f6f4(              \
      afv, bf1, acc[mt][1], 0, 0, 0, SCALE1, 0, SCALE1);                      \
  acc[mt][2] = __builtin_amdgcn_mfma_scale_f32_16x16x128_f8f6f4(              \
      afv, bf2, acc[mt][2], 0, 0, 0, SCALE1, 0, SCALE1);                      \
  acc[mt][3] = __builtin_amdgcn_mfma_scale_f32_16x16x128_f8f6f4(              \
      afv, bf3, acc[mt][3], 0, 0, 0, SCALE1, 0, SCALE1)
        MFMA_ROW(0, af0);
        MFMA_ROW(1, af1);
        MFMA_ROW(2, af2);
        MFMA_ROW(3, af3);
#undef MFMA_ROW
        __syncthreads();  // all frag reads done before next kt's ds_writes
      }

      // epilogue: s = 2*acc; masked cols store pos; sums of exp otherwise
      const int r0 = rt * 128 + wr * 64;
      const int c0 = ct * 128 + wc * 64;
      float cs[4] = {0.f, 0.f, 0.f, 0.f};
#pragma unroll
      for (int mt = 0; mt < 4; ++mt) {
        float rs[4] = {0.f, 0.f, 0.f, 0.f};
#pragma unroll
        for (int nt = 0; nt < 4; ++nt) {
          const int c = c0 + nt * 16 + m;
#pragma unroll
          for (int reg = 0; reg < 4; ++reg) {
            const int r = r0 + mt * 16 + q * 4 + reg;
            const float sv = acc[mt][nt][reg] * 2.0f;
            if (((c - r) & (NB - 1)) == 0) {
              pos[r * NV + (c >> 11)] = sv;
              if (!diag) pos[c * NV + (r >> 11)] = sv;
            } else {
              const float e = __expf(sv);
              rs[reg] += e;
              cs[nt] += e;
            }
          }
        }
#pragma unroll
        for (int off = 1; off < 16; off <<= 1) {
#pragma unroll
          for (int reg = 0; reg < 4; ++reg) rs[reg] += __shfl_xor(rs[reg], off, 64);
        }
        if (m < 4) atomicAdd(&sumexp[r0 + mt * 16 + q * 4 + m], rs[m]);
      }
      if (!diag) {
#pragma unroll
        for (int nt = 0; nt < 4; ++nt) {
          cs[nt] += __shfl_xor(cs[nt], 16, 64);
          cs[nt] += __shfl_xor(cs[nt], 32, 64);
        }
        if (q == 0) {
#pragma unroll
          for (int nt = 0; nt < 4; ++nt)
            atomicAdd(&sumexp[c0 + nt * 16 + m], cs[nt]);
        }
      }
    }
  }

  grid.sync();  // sumexp/pos complete

  // ===================== phase 3: finalize ==================================
  if (bid0 < NN / 256) {
    const int r = bid0 * 256 + tid;
    const float se = sumexp[r];
    const int i = r >> 11;
    float local = 0.0f;
#pragma unroll
    for (int j = 0; j < NV; ++j) {
      if (j == i) continue;
      const float p = pos[r * NV + j];
      local += logf(__expf(p) + se) - p;
    }
    local *= (1.0f / NB);
#pragma unroll
    for (int off = 32; off > 0; off >>= 1) local += __shfl_xor(local, off, 64);
    if ((tid & 63) == 0) atomicAdd(out, local);
  }
}

// ======================= fallback 3-kernel path (R7) ========================
__global__ __launch_bounds__(256) void normalize_k(const float* __restrict__ x,
                                                   unsigned char* __restrict__ xn,
                                                   float* __restrict__ sumexp,
                                                   float* __restrict__ out) {
  if (threadIdx.x < 4) sumexp[blockIdx.x * 4 + threadIdx.x] = 0.0f;
  if (blockIdx.x == 0 && threadIdx.x == 0) out[0] = 0.0f;
  const int row = blockIdx.x * 4 + (threadIdx.x >> 6);
  const int l = threadIdx.x & 63;
  const float4* xr = (const float4*)(x + (size_t)row * ND);
  float4 v0 = xr[l * 2 + 0];
  float4 v1 = xr[l * 2 + 1];
  float ss = v0.x * v0.x + v0.y * v0.y + v0.z * v0.z + v0.w * v0.w +
             v1.x * v1.x + v1.y * v1.y + v1.z * v1.z + v1.w * v1.w;
#pragma unroll
  for (int off = 32; off > 0; off >>= 1) ss += __shfl_xor(ss, off, 64);
  const float inv = 1.0f / fmaxf(sqrtf(ss), 1e-8f);
  union { unsigned char b[8]; uint2 u; } pk;
  pk.b[0] = __hip_fp8_e4m3(v0.x * inv).__x;
  pk.b[1] = __hip_fp8_e4m3(v0.y * inv).__x;
  pk.b[2] = __hip_fp8_e4m3(v0.z * inv).__x;
  pk.b[3] = __hip_fp8_e4m3(v0.w * inv).__x;
  pk.b[4] = __hip_fp8_e4m3(v1.x * inv).__x;
  pk.b[5] = __hip_fp8_e4m3(v1.y * inv).__x;
  pk.b[6] = __hip_fp8_e4m3(v1.z * inv).__x;
  pk.b[7] = __hip_fp8_e4m3(v1.w * inv).__x;
  *(uint2*)(xn + (size_t)row * ND + l * 8) = pk.u;
}

__global__ __launch_bounds__(256) void finalize_k(
    const float* __restrict__ sumexp, const float* __restrict__ pos,
    float* __restrict__ out) {
  const int r = blockIdx.x * 256 + threadIdx.x;
  const float se = sumexp[r];
  const int i = r >> 11;
  float local = 0.0f;
#pragma unroll
  for (int j = 0; j < NV; ++j) {
    if (j == i) continue;
    const float p = pos[r * NV + j];
    local += logf(__expf(p) + se) - p;
  }
  local *= (1.0f / NB);
#pragma unroll
  for (int off = 32; off > 0; off >>= 1) local += __shfl_xor(local, off, 64);
  if ((threadIdx.x & 63) == 0) atomicAdd(out, local);
}

// sim fallback: launch fused_k's phase-2 logic standalone is not possible;
// reuse fused_k only cooperatively. Fallback sim uses the R7 standalone sim.
__global__ __launch_bounds__(256) void sim_k(const unsigned char* __restrict__ xn,
                                             float* __restrict__ sumexp,
                                             float* __restrict__ pos) {
  __shared__ unsigned char As[128 * 128];
  __shared__ unsigned char Bs[128 * 128];
  const int tid = threadIdx.x;
  const int l = tid & 63;
  const int m = l & 15, q = l >> 4, s = l & 7;
  const int wr = (tid >> 6) >> 1, wc = (tid >> 6) & 1;
  const int bid = blockIdx.x;
  int rt = (int)((129.0f - sqrtf(16641.0f - 8.0f * (float)bid)) * 0.5f);
  rt = rt < 0 ? 0 : (rt > 63 ? 63 : rt);
  while (rt > 0 && (rt * 64 - rt * (rt - 1) / 2) > bid) --rt;
  while (rt < 63 && ((rt + 1) * 64 - (rt + 1) * rt / 2) <= bid) ++rt;
  const int ct = rt + (bid - (rt * 64 - rt * (rt - 1) / 2));
  const bool diag = (rt == ct);
  floatx4 acc[4][4] = {};
  const unsigned char* gA = xn + (size_t)rt * 128 * ND;
  const unsigned char* gB = xn + (size_t)ct * 128 * ND;
  const int crow = tid >> 3;
  const int coff = (tid & 7) * 16;
  const int lsw = ((tid & 7) ^ ((tid >> 3) & 7)) * 16;
  const int fo0 = ((2 * q + 0) ^ s) * 16;
  const int fo1 = ((2 * q + 1) ^ s) * 16;
  int4v pA[4], pB[4];
#pragma unroll
  for (int i = 0; i < 4; ++i) {
    const size_t go = (size_t)(i * 32 + crow) * ND + coff;
    pA[i] = *(const int4v*)(gA + go);
    pB[i] = *(const int4v*)(gB + go);
  }
#pragma unroll 1
  for (int kt = 0; kt < 4; ++kt) {
#pragma unroll
    for (int i = 0; i < 4; ++i) {
      const int la = (i * 32 + crow) * 128 + lsw;
      *(int4v*)(As + la) = pA[i];
      *(int4v*)(Bs + la) = pB[i];
    }
    __syncthreads();
    if (kt < 3) {
      const int kb = (kt + 1) * 128;
#pragma unroll
      for (int i = 0; i < 4; ++i) {
        const size_t go = (size_t)(i * 32 + crow) * ND + kb + coff;
        pA[i] = *(const int4v*)(gA + go);
        pB[i] = *(const int4v*)(gB + go);
      }
    }
    int8v af0, af1, af2, af3, bf0, bf1, bf2, bf3;
    {
      const unsigned char* pa0 = As + (wr * 64 + 0 * 16 + m) * 128;
      const unsigned char* pa1 = As + (wr * 64 + 1 * 16 + m) * 128;
      const unsigned char* pa2 = As + (wr * 64 + 2 * 16 + m) * 128;
      const unsigned char* pa3 = As + (wr * 64 + 3 * 16 + m) * 128;
      const unsigned char* pb0 = Bs + (wc * 64 + 0 * 16 + m) * 128;
      const unsigned char* pb1 = Bs + (wc * 64 + 1 * 16 + m) * 128;
      const unsigned char* pb2 = Bs + (wc * 64 + 2 * 16 + m) * 128;
      const unsigned char* pb3 = Bs + (wc * 64 + 3 * 16 + m) * 128;
      af0 = __builtin_shufflevector(*(const int4v*)(pa0 + fo0),
                                    *(const int4v*)(pa0 + fo1), 0,1,2,3,4,5,6,7);
      af1 = __builtin_shufflevector(*(const int4v*)(pa1 + fo0),
                                    *(const int4v*)(pa1 + fo1), 0,1,2,3,4,5,6,7);
      af2 = __builtin_shufflevector(*(const int4v*)(pa2 + fo0),
                                    *(const int4v*)(pa2 + fo1), 0,1,2,3,4,5,6,7);
      af3 = __builtin_shufflevector(*(const int4v*)(pa3 + fo0),
                                    *(const int4v*)(pa3 + fo1), 0,1,2,3,4,5,6,7);
      bf0 = __builtin_shufflevector(*(const int4v*)(pb0 + fo0),
                                    *(const int4v*)(pb0 + fo1), 0,1,2,3,4,5,6,7);
      bf1 = __builtin_shufflevector(*(const int4v*)(pb1 + fo0),
                                    *(const int4v*)(pb1 + fo1), 0,1,2,3,4,5,6,7);
      bf2 = __builtin_shufflevector(*(const int4v*)(pb2 + fo0),
                                    *(const int4v*)(pb2 + fo1), 0,1,2,3,4,5,6,7);
      bf3 = __builtin_shufflevector(*(const int4v*)(pb3 + fo0),
                                    *(const int4v*)(pb3 + fo1), 0,1,2,3,4,5,6,7);
    }
#define MFMA_ROW(mt, afv)                                                     \
  acc[mt][0] = __builtin_amdgcn_mfma_scale_f32_16x16x128_f8f6f4(              \
      afv, bf0, acc[mt][0], 0, 0, 0, SCALE1, 0, SCALE1);                      \
  acc[mt][1] = __builtin_amdgcn_mfma_scale_f32_16x16x128_f8f6f4(              \
      afv, bf1, acc[mt][1], 0, 0, 0, SCALE1, 0, SCALE1);                      \
  acc[mt][2] = __builtin_amdgcn_mfma_scale_f32_16x16x128_f8f6f4(              \
      afv, bf2, acc[mt][2], 0, 0, 0, SCALE1, 0, SCALE1);                      \
  acc[mt][3] = __builtin_amdgcn_mfma_scale_f32_16x16x128_f8f6f4(              \
      afv, bf3, acc[mt][3], 0, 0, 0, SCALE1, 0, SCALE1)
    MFMA_ROW(0, af0);
    MFMA_ROW(1, af1);
    MFMA_ROW(2, af2);
    MFMA_ROW(3, af3);
#undef MFMA_ROW
    __syncthreads();
  }
  const int r0 = rt * 128 + wr * 64;
  const int c0 = ct * 128 + wc * 64;
  float cs[4] = {0.f, 0.f, 0.f, 0.f};
#pragma unroll
  for (int mt = 0; mt < 4; ++mt) {
    float rs[4] = {0.f, 0.f, 0.f, 0.f};
#pragma unroll
    for (int nt = 0; nt < 4; ++nt) {
      const int c = c0 + nt * 16 + m;
#pragma unroll
      for (int reg = 0; reg < 4; ++reg) {
        const int r = r0 + mt * 16 + q * 4 + reg;
        const float sv = acc[mt][nt][reg] * 2.0f;
        if (((c - r) & (NB - 1)) == 0) {
          pos[r * NV + (c >> 11)] = sv;
          if (!diag) pos[c * NV + (r >> 11)] = sv;
        } else {
          const float e = __expf(sv);
          rs[reg] += e;
          cs[nt] += e;
        }
      }
    }
#pragma unroll
    for (int off = 1; off < 16; off <<= 1) {
#pragma unroll
      for (int reg = 0; reg < 4; ++reg) rs[reg] += __shfl_xor(rs[reg], off, 64);
    }
    if (m < 4) atomicAdd(&sumexp[r0 + mt * 16 + q * 4 + m], rs[m]);
  }
  if (!diag) {
#pragma unroll
    for (int nt = 0; nt < 4; ++nt) {
      cs[nt] += __shfl_xor(cs[nt], 16, 64);
      cs[nt] += __shfl_xor(cs[nt], 32, 64);
    }
    if (q == 0) {
#pragma unroll
      for (int nt = 0; nt < 4; ++nt)
        atomicAdd(&sumexp[c0 + nt * 16 + m], cs[nt]);
    }
  }
}

extern "C" void kernel_launch(void* const* d_in, const int* in_sizes, int n_in,
                              void* d_out, int out_size, void* d_ws,
                              size_t ws_size, hipStream_t stream) {
  const float* x = (const float*)d_in[0];
  float* out = (float*)d_out;
  char* ws = (char*)d_ws;
  unsigned char* xn = (unsigned char*)ws;                 // 4 MB fp8
  float* sumexp = (float*)(ws + (size_t)NN * ND);         // 32 KB
  float* pos = (float*)(ws + (size_t)NN * ND + NN * 4);   // 128 KB

  void* args[] = {(void*)&x, (void*)&xn, (void*)&sumexp, (void*)&pos,
                  (void*)&out};
  hipError_t err = hipLaunchCooperativeKernel(
      (const void*)(const void*)fused_k, dim3(512), dim3(256), args, 0, stream);
  if (err != hipSuccess) {
    // fallback: proven 3-kernel R7 path (~110 µs)
    normalize_k<<<NN / 4, 256, 0, stream>>>(x, xn, sumexp, out);
    sim_k<<<64 * 65 / 2, 256, 0, stream>>>(xn, sumexp, pos);
    finalize_k<<<NN / 256, 256, 0, stream>>>(sumexp, pos, out);
  }
}

// Round 7
// 99.956 us; speedup vs baseline: 2.2202x; 2.2202x over previous
//
#include <hip/hip_runtime.h>
#include <hip/hip_fp8.h>

#define NV 4
#define NB 2048
#define ND 512
#define NN 8192
// sim = cos/TEMP, TEMP=0.5 -> scale 2.0

typedef int int8v __attribute__((ext_vector_type(8)));
typedef int int4v __attribute__((ext_vector_type(4)));
typedef float floatx4 __attribute__((ext_vector_type(4)));
#define SCALE1 0x7F7F7F7Fu  // E8M0 bytes 127 -> 2^0 = 1.0

// ============================================================================
// R14: NO-LDS sim — xn stored in MFMA-fragment layout.
// R13 proved the ~62-71 µs residual is fixed harness overhead (persists with
// a single fused kernel) -> revert to 3-kernel chain; minimize kernel time.
// R7 analysis: kt loop is LDS-pipe-bound (64 ds_read_b128 ~770 cy vs 140 cy
// MFMA per kt) plus ds_writes + 2 barriers/kt at ~1.3 blocks/CU. All of that
// machinery only fixes fragment-read coalescing — but WE write xn. So
// normalize_k now emits xn in the fragment layout itself:
//   xn[R][C][m][b]  (R=row>>4, C=k>>5, m=row&15, b=k&31)
//   linear offset = R*8192 + C*512 + m*32 + b
// A wave's MFMA operand (lane(m,q) needs row m, k in [32q,32q+32)) is then
// 2 KB FULLY CONTIGUOUS per fragment, loaded straight from global (xn is
// 4 MB -> L2-resident; intra-block x2 reuse often L1-hits). sim_k loses LDS,
// staging, swizzles and ALL barriers: per kt, 16 coalesced
// global_load_dwordx4 + 16 MFMA; waves fully independent (pure TLP).
// Floors: L2 532 MB @ 34.5 TB/s ~ 15 µs; MFMA ~7.5 µs.
// ============================================================================

// ---------------- normalize: x[N,D] f32 -> xn fragment-layout fp8 ----------
__global__ __launch_bounds__(256) void normalize_k(const float* __restrict__ x,
                                                   unsigned char* __restrict__ xn,
                                                   float* __restrict__ sumexp,
                                                   float* __restrict__ out) {
  if (threadIdx.x < 4) sumexp[blockIdx.x * 4 + threadIdx.x] = 0.0f;
  if (blockIdx.x == 0 && threadIdx.x == 0) out[0] = 0.0f;

  const int row = blockIdx.x * 4 + (threadIdx.x >> 6);  // one wave per row
  const int l = threadIdx.x & 63;                        // lane: cols [8l, 8l+8)
  const float4* xr = (const float4*)(x + (size_t)row * ND);
  float4 v0 = xr[l * 2 + 0];
  float4 v1 = xr[l * 2 + 1];
  float ss = v0.x * v0.x + v0.y * v0.y + v0.z * v0.z + v0.w * v0.w +
             v1.x * v1.x + v1.y * v1.y + v1.z * v1.z + v1.w * v1.w;
#pragma unroll
  for (int off = 32; off > 0; off >>= 1) ss += __shfl_xor(ss, off, 64);
  const float inv = 1.0f / fmaxf(sqrtf(ss), 1e-8f);
  union { unsigned char b[8]; uint2 u; } pk;
  pk.b[0] = __hip_fp8_e4m3(v0.x * inv).__x;
  pk.b[1] = __hip_fp8_e4m3(v0.y * inv).__x;
  pk.b[2] = __hip_fp8_e4m3(v0.z * inv).__x;
  pk.b[3] = __hip_fp8_e4m3(v0.w * inv).__x;
  pk.b[4] = __hip_fp8_e4m3(v1.x * inv).__x;
  pk.b[5] = __hip_fp8_e4m3(v1.y * inv).__x;
  pk.b[6] = __hip_fp8_e4m3(v1.z * inv).__x;
  pk.b[7] = __hip_fp8_e4m3(v1.w * inv).__x;
  // fragment layout: k-bytes [8l,8l+8) -> chunk C=l>>2, intra b=(l&3)*8
  const int R = row >> 4, mm = row & 15;
  *(uint2*)(xn + (size_t)R * 8192 + (l >> 2) * 512 + mm * 32 + (l & 3) * 8) =
      pk.u;
}

// ---------------- sim: barrier-free, LDS-free, direct-fragment GEMM --------
// Per wave: 64x64 output at (wr*64, wc*64) of the 128^2 tile. Per kt:
// 8 fragments, each two dwordx4 from a contiguous 2 KB run; 16 MFMA.
__global__ __launch_bounds__(256) void sim_k(const unsigned char* __restrict__ xn,
                                             float* __restrict__ sumexp,
                                             float* __restrict__ pos) {
  const int tid = threadIdx.x;
  const int l = tid & 63;
  const int m = l & 15, q = l >> 4;
  const int wr = (tid >> 6) >> 1, wc = (tid >> 6) & 1;

  // XCD swizzle (2080 = 8*260, bijective) for L2 locality
  const int bid = (blockIdx.x & 7) * 260 + (blockIdx.x >> 3);
  // triangular decode: bid -> (rt, ct), rt <= ct
  int rt = (int)((129.0f - sqrtf(16641.0f - 8.0f * (float)bid)) * 0.5f);
  rt = rt < 0 ? 0 : (rt > 63 ? 63 : rt);
  while (rt > 0 && (rt * 64 - rt * (rt - 1) / 2) > bid) --rt;
  while (rt < 63 && ((rt + 1) * 64 - (rt + 1) * rt / 2) <= bid) ++rt;
  const int ct = rt + (bid - (rt * 64 - rt * (rt - 1) / 2));
  const bool diag = (rt == ct);

  floatx4 acc[4][4] = {};

  // lane base inside a fragment block: chunk q (512 B), row m (32 B)
  const unsigned char* pa =
      xn + (size_t)(rt * 8 + wr * 4) * 8192 + q * 512 + m * 32;
  const unsigned char* pb =
      xn + (size_t)(ct * 8 + wc * 4) * 8192 + q * 512 + m * 32;

#define LDFRAG(dst, base, mt, kt)                                            \
  do {                                                                       \
    const unsigned char* p_ = (base) + (mt) * 8192 + (kt) * 2048;            \
    dst = __builtin_shufflevector(*(const int4v*)(p_),                       \
                                  *(const int4v*)(p_ + 16),                  \
                                  0, 1, 2, 3, 4, 5, 6, 7);                   \
  } while (0)

#pragma unroll 1  // rolled: 64 hoisted loads would spill (R10 lesson)
  for (int kt = 0; kt < 4; ++kt) {
    int8v af0, af1, af2, af3, bf0, bf1, bf2, bf3;
    LDFRAG(af0, pa, 0, kt);
    LDFRAG(af1, pa, 1, kt);
    LDFRAG(af2, pa, 2, kt);
    LDFRAG(af3, pa, 3, kt);
    LDFRAG(bf0, pb, 0, kt);
    LDFRAG(bf1, pb, 1, kt);
    LDFRAG(bf2, pb, 2, kt);
    LDFRAG(bf3, pb, 3, kt);
#define MFMA_ROW(mt, afv)                                                    \
  acc[mt][0] = __builtin_amdgcn_mfma_scale_f32_16x16x128_f8f6f4(             \
      afv, bf0, acc[mt][0], 0, 0, 0, SCALE1, 0, SCALE1);                     \
  acc[mt][1] = __builtin_amdgcn_mfma_scale_f32_16x16x128_f8f6f4(             \
      afv, bf1, acc[mt][1], 0, 0, 0, SCALE1, 0, SCALE1);                     \
  acc[mt][2] = __builtin_amdgcn_mfma_scale_f32_16x16x128_f8f6f4(             \
      afv, bf2, acc[mt][2], 0, 0, 0, SCALE1, 0, SCALE1);                     \
  acc[mt][3] = __builtin_amdgcn_mfma_scale_f32_16x16x128_f8f6f4(             \
      afv, bf3, acc[mt][3], 0, 0, 0, SCALE1, 0, SCALE1)
    MFMA_ROW(0, af0);
    MFMA_ROW(1, af1);
    MFMA_ROW(2, af2);
    MFMA_ROW(3, af3);
#undef MFMA_ROW
  }

  // epilogue: s = 2*acc; masked cols ((c-r)%B==0) store pos, skip sums.
  // Row sums always; col sums + pos mirror only on off-diagonal tiles.
  const int r0 = rt * 128 + wr * 64;
  const int c0 = ct * 128 + wc * 64;
  float cs[4] = {0.f, 0.f, 0.f, 0.f};  // per-nt column partials (this lane's q)
#pragma unroll
  for (int mt = 0; mt < 4; ++mt) {
    float rs[4] = {0.f, 0.f, 0.f, 0.f};
#pragma unroll
    for (int nt = 0; nt < 4; ++nt) {
      const int c = c0 + nt * 16 + m;  // C layout: col = lane&15
#pragma unroll
      for (int reg = 0; reg < 4; ++reg) {
        const int r = r0 + mt * 16 + q * 4 + reg;  // row = quad*4 + reg
        const float sv = acc[mt][nt][reg] * 2.0f;
        if (((c - r) & (NB - 1)) == 0) {
          pos[r * NV + (c >> 11)] = sv;  // includes j==i (unused later)
          if (!diag) pos[c * NV + (r >> 11)] = sv;
        } else {
          const float e = __expf(sv);
          rs[reg] += e;
          cs[nt] += e;
        }
      }
    }
    // reduce rows across the 16-lane column dimension (m)
#pragma unroll
    for (int off = 1; off < 16; off <<= 1) {
#pragma unroll
      for (int reg = 0; reg < 4; ++reg) rs[reg] += __shfl_xor(rs[reg], off, 64);
    }
    if (m < 4) atomicAdd(&sumexp[r0 + mt * 16 + q * 4 + m], rs[m]);
  }
  if (!diag) {
    // reduce cols across the 4-quad row dimension (q)
#pragma unroll
    for (int nt = 0; nt < 4; ++nt) {
      cs[nt] += __shfl_xor(cs[nt], 16, 64);
      cs[nt] += __shfl_xor(cs[nt], 32, 64);
    }
    if (q == 0) {
#pragma unroll
      for (int nt = 0; nt < 4; ++nt)
        atomicAdd(&sumexp[c0 + nt * 16 + m], cs[nt]);
    }
  }
}

// ---------------- finalize: scalar loss -------------------------------------
__global__ __launch_bounds__(256) void finalize_k(
    const float* __restrict__ sumexp, const float* __restrict__ pos,
    float* __restrict__ out) {
  const int r = blockIdx.x * 256 + threadIdx.x;
  const float se = sumexp[r];
  const int i = r >> 11;  // view index
  float local = 0.0f;
#pragma unroll
  for (int j = 0; j < NV; ++j) {
    if (j == i) continue;
    const float p = pos[r * NV + j];
    local += logf(__expf(p) + se) - p;  // logaddexp(pos, lse_neg) - pos
  }
  local *= (1.0f / NB);
#pragma unroll
  for (int off = 32; off > 0; off >>= 1) local += __shfl_xor(local, off, 64);
  if ((threadIdx.x & 63) == 0) atomicAdd(out, local);
}

extern "C" void kernel_launch(void* const* d_in, const int* in_sizes, int n_in,
                              void* d_out, int out_size, void* d_ws,
                              size_t ws_size, hipStream_t stream) {
  const float* x = (const float*)d_in[0];
  float* out = (float*)d_out;
  char* ws = (char*)d_ws;
  unsigned char* xn = (unsigned char*)ws;                 // 4 MB fp8 (frag layout)
  float* sumexp = (float*)(ws + (size_t)NN * ND);         // 32 KB
  float* pos = (float*)(ws + (size_t)NN * ND + NN * 4);   // 128 KB

  normalize_k<<<NN / 4, 256, 0, stream>>>(x, xn, sumexp, out);
  sim_k<<<64 * 65 / 2, 256, 0, stream>>>(xn, sumexp, pos);
  finalize_k<<<NN / 256, 256, 0, stream>>>(sumexp, pos, out);
}